// Round 1
// baseline (7920.757 us; speedup 1.0000x reference)
//
#include <hip/hip_runtime.h>
#include <math.h>

#define LSTRIDE 68  // 64 + 4 pad: keeps rows 16B-aligned, skews banks

// acc[j] += sum_k rows[r][k] * bcast[k][cc*16 + j]   (OUT = ROWS * BCAST)
__device__ __forceinline__ void mm16(float acc[16], const float* rows,
                                     const float* bcast, int r, int cc) {
  const float* rowp = rows + r * LSTRIDE;
  const float* bc   = bcast + cc * 16;
#pragma unroll 2
  for (int kb = 0; kb < 8; ++kb) {
    float4 u0 = *(const float4*)(rowp + 8 * kb);
    float4 u1 = *(const float4*)(rowp + 8 * kb + 4);
    float u[8] = {u0.x, u0.y, u0.z, u0.w, u1.x, u1.y, u1.z, u1.w};
#pragma unroll
    for (int dk = 0; dk < 8; ++dk) {
      const float* tp = bc + (8 * kb + dk) * LSTRIDE;
      float4 t0 = *(const float4*)(tp + 0);
      float4 t1 = *(const float4*)(tp + 4);
      float4 t2 = *(const float4*)(tp + 8);
      float4 t3 = *(const float4*)(tp + 12);
      float uv = u[dk];
      acc[0]  = fmaf(uv, t0.x, acc[0]);
      acc[1]  = fmaf(uv, t0.y, acc[1]);
      acc[2]  = fmaf(uv, t0.z, acc[2]);
      acc[3]  = fmaf(uv, t0.w, acc[3]);
      acc[4]  = fmaf(uv, t1.x, acc[4]);
      acc[5]  = fmaf(uv, t1.y, acc[5]);
      acc[6]  = fmaf(uv, t1.z, acc[6]);
      acc[7]  = fmaf(uv, t1.w, acc[7]);
      acc[8]  = fmaf(uv, t2.x, acc[8]);
      acc[9]  = fmaf(uv, t2.y, acc[9]);
      acc[10] = fmaf(uv, t2.z, acc[10]);
      acc[11] = fmaf(uv, t2.w, acc[11]);
      acc[12] = fmaf(uv, t3.x, acc[12]);
      acc[13] = fmaf(uv, t3.y, acc[13]);
      acc[14] = fmaf(uv, t3.z, acc[14]);
      acc[15] = fmaf(uv, t3.w, acc[15]);
    }
  }
}

extern "C" __global__ void __launch_bounds__(256, 3)
logeig_kernel(const float* __restrict__ in, float* __restrict__ out) {
  __shared__ __align__(16) float BY[64 * LSTRIDE];
  __shared__ __align__(16) float BT[64 * LSTRIDE];
  __shared__ __align__(16) float BZ[64 * LSTRIDE];
  __shared__ float red[4];

  const int b   = blockIdx.x;
  const int tid = threadIdx.x;
  const int r   = tid >> 2;   // output row 0..63 (4 lanes per row)
  const int cc  = tid & 3;    // 16-col chunk 0..3
  const float* A = in + (size_t)b * 4096;

  // ---- coalesced load -> BY ----
  {
    const float4* A4 = (const float4*)A;
#pragma unroll
    for (int i = 0; i < 4; ++i) {
      int f = tid + 256 * i;          // float4 index 0..1023
      float4 v = A4[f];
      int row = f >> 4;
      int col = (f & 15) << 2;
      *(float4*)(&BY[row * LSTRIDE + col]) = v;
    }
  }
  __syncthreads();

  // ---- c = ||A||_inf (Gershgorin bound on lambda_max) ----
  {
    const float* rp = BY + r * LSTRIDE + cc * 16;
    float s = 0.f;
#pragma unroll
    for (int i = 0; i < 16; ++i) s += fabsf(rp[i]);
    s += __shfl_xor(s, 1);
    s += __shfl_xor(s, 2);           // full row abs-sum in all 4 lanes of the row
#pragma unroll
    for (int off = 4; off < 64; off <<= 1) s = fmaxf(s, __shfl_xor(s, off));
    if ((tid & 63) == 0) red[tid >> 6] = s;
  }
  __syncthreads();
  const float c     = fmaxf(fmaxf(red[0], red[1]), fmaxf(red[2], red[3]));
  const float inv_c = 1.0f / c;
  const float log_c = logf(c);

  // ---- Y = A / c (own chunk) ----
  {
    float* rp = BY + r * LSTRIDE + cc * 16;
#pragma unroll
    for (int i = 0; i < 4; ++i) {
      float4 v = *(float4*)(rp + 4 * i);
      v.x *= inv_c; v.y *= inv_c; v.z *= inv_c; v.w *= inv_c;
      *(float4*)(rp + 4 * i) = v;
    }
  }
  __syncthreads();

  // ---- 3 sqrt levels, coupled Newton-Schulz ----
#pragma unroll 1
  for (int lvl = 0; lvl < 3; ++lvl) {
    const int ni = (lvl == 0) ? 8 : ((lvl == 1) ? 6 : 5);
#pragma unroll 1
    for (int it = 0; it < ni; ++it) {
      float t[16];
      if (it == 0) {
        // T = (3I - Y)/2 directly (Z0 = I)
        const float* rp = BY + r * LSTRIDE + cc * 16;
#pragma unroll
        for (int j = 0; j < 16; ++j) {
          float d = (cc * 16 + j == r) ? 3.0f : 0.0f;
          t[j] = 0.5f * (d - rp[j]);
        }
      } else {
        float p[16];
#pragma unroll
        for (int j = 0; j < 16; ++j) p[j] = 0.f;
        mm16(p, BZ, BY, r, cc);       // P = Z*Y
#pragma unroll
        for (int j = 0; j < 16; ++j) {
          float d = (cc * 16 + j == r) ? 3.0f : 0.0f;
          t[j] = 0.5f * (d - p[j]);
        }
      }
      {
        float* tp = BT + r * LSTRIDE + cc * 16;
#pragma unroll
        for (int j = 0; j < 16; ++j) tp[j] = t[j];
        if (it == 0) {                 // Z1 = T0
          float* zp = BZ + r * LSTRIDE + cc * 16;
#pragma unroll
          for (int j = 0; j < 16; ++j) zp[j] = t[j];
        }
      }
      __syncthreads();                 // T visible for bcast reads

      float ay[16];
#pragma unroll
      for (int j = 0; j < 16; ++j) ay[j] = 0.f;
      mm16(ay, BY, BT, r, cc);         // Y' = Y*T
      if (it > 0) {
        float az[16];
#pragma unroll
        for (int j = 0; j < 16; ++j) az[j] = 0.f;
        mm16(az, BZ, BT, r, cc);       // Z' = Z*T (= T*Z, commuting)
        float* zp = BZ + r * LSTRIDE + cc * 16;
#pragma unroll
        for (int j = 0; j < 16; ++j) zp[j] = az[j];
      }
      {
        float* yp = BY + r * LSTRIDE + cc * 16;
#pragma unroll
        for (int j = 0; j < 16; ++j) yp[j] = ay[j];
      }
      __syncthreads();                 // Y/Z visible for next iteration
    }
  }

  // ---- series: X = Y - I (in BY), Q = (1/7) I (in BT) ----
  {
    float* yp = BY + r * LSTRIDE + cc * 16;
    float* tp = BT + r * LSTRIDE + cc * 16;
#pragma unroll
    for (int j = 0; j < 16; ++j) {
      int col = cc * 16 + j;
      if (col == r) yp[j] -= 1.0f;
      tp[j] = (col == r) ? (1.0f / 7.0f) : 0.0f;
    }
  }
  __syncthreads();

  // Horner: Q = c_t I + Q*X,  t = 5..0 ; coefs (-1)^t/(t+1)
  const float coef[6] = {-1.f / 6.f, 0.2f, -0.25f, 1.f / 3.f, -0.5f, 1.0f};
#pragma unroll 1
  for (int s = 0; s < 6; ++s) {
    float q[16];
#pragma unroll
    for (int j = 0; j < 16; ++j) q[j] = 0.f;
    mm16(q, BT, BY, r, cc);            // Q*X
    float* tp = BT + r * LSTRIDE + cc * 16;
#pragma unroll
    for (int j = 0; j < 16; ++j) {
      int col = cc * 16 + j;
      tp[j] = q[j] + ((col == r) ? coef[s] : 0.0f);
    }
    __syncthreads();
  }

  // Lsmall = Q*X ; L = 8*Lsmall + log(c) I ; abs, sqrt2 off-diag, triu gather
  float fl[16];
#pragma unroll
  for (int j = 0; j < 16; ++j) fl[j] = 0.f;
  mm16(fl, BT, BY, r, cc);

  const float SQ2 = 1.41421356237309515f;
  const size_t rowoff = (size_t)b * 2080 + (size_t)(r * 64 - (r * (r - 1)) / 2 - r);
#pragma unroll
  for (int j = 0; j < 16; ++j) {
    int col = cc * 16 + j;
    if (col >= r) {
      float v = 8.0f * fl[j] + ((col == r) ? log_c : 0.0f);
      v = fabsf(v) * ((col == r) ? 1.0f : SQ2);
      out[rowoff + col] = v;
    }
  }
}

extern "C" void kernel_launch(void* const* d_in, const int* in_sizes, int n_in,
                              void* d_out, int out_size, void* d_ws, size_t ws_size,
                              hipStream_t stream) {
  (void)n_in; (void)d_ws; (void)ws_size; (void)out_size;
  const float* in = (const float*)d_in[0];
  float* out = (float*)d_out;
  const int B = in_sizes[0] / 4096;   // 16384
  hipLaunchKernelGGL(logeig_kernel, dim3(B), dim3(256), 0, stream, in, out);
}

// Round 2
// 1810.724 us; speedup vs baseline: 4.3744x; 4.3744x over previous
//
#include <hip/hip_runtime.h>
#include <math.h>

#define PLANE 4352   // 64 rows * 68 shorts
#define RS 68        // row stride (elements); 136 B = 34 banks -> 2-way max, free

typedef short s4v __attribute__((ext_vector_type(4)));
typedef short s8v __attribute__((ext_vector_type(8)));
typedef float f16v __attribute__((ext_vector_type(16)));

__device__ __forceinline__ float fb(short s) {
  return __uint_as_float(((unsigned)(unsigned short)s) << 16);
}
__device__ __forceinline__ short tb(float x) {  // truncate to bf16
  return (short)(__float_as_uint(x) >> 16);
}

// Load hi/lo fragment sets of symmetric matrix quadrant q:
// lane (lr,h) gets rows 32q+lr, cols ks*16+8h..+7  (A-frag == B-frag by symmetry)
__device__ __forceinline__ void load_fs(const short* Ph, const short* Pl, int q,
                                        int lr, int h, s8v fh[4], s8v fl[4]) {
  const int off = (32 * q + lr) * RS + 8 * h;
  const short* ph = Ph + off;
  const short* pl = Pl + off;
#pragma unroll
  for (int ks = 0; ks < 4; ++ks) {
    s4v a = *(const s4v*)(ph + 16 * ks);
    s4v b = *(const s4v*)(ph + 16 * ks + 4);
    fh[ks] = __builtin_shufflevector(a, b, 0, 1, 2, 3, 4, 5, 6, 7);
    s4v c = *(const s4v*)(pl + 16 * ks);
    s4v d = *(const s4v*)(pl + 16 * ks + 4);
    fl[ks] = __builtin_shufflevector(c, d, 0, 1, 2, 3, 4, 5, 6, 7);
  }
}

// C = A*B with hi/lo split: 12 MFMAs (drop lo*lo ~ 2^-32)
__device__ __forceinline__ f16v mm3p(const s8v Ah[4], const s8v Al[4],
                                     const s8v Bh[4], const s8v Bl[4]) {
  f16v acc = {0.f, 0.f, 0.f, 0.f, 0.f, 0.f, 0.f, 0.f,
              0.f, 0.f, 0.f, 0.f, 0.f, 0.f, 0.f, 0.f};
#pragma unroll
  for (int ks = 0; ks < 4; ++ks) {
    acc = __builtin_amdgcn_mfma_f32_32x32x16_bf16(Ah[ks], Bh[ks], acc, 0, 0, 0);
    acc = __builtin_amdgcn_mfma_f32_32x32x16_bf16(Ah[ks], Bl[ks], acc, 0, 0, 0);
    acc = __builtin_amdgcn_mfma_f32_32x32x16_bf16(Al[ks], Bh[ks], acc, 0, 0, 0);
  }
  return acc;
}

// Store quadrant result (A-quad qa rows, B-quad qb cols) TRANSPOSED (result is
// symmetric): LDS[32qb+lr][32qa + (t+8g+4h)] = aa*v + bd on the true diagonal.
// Per g: 4 contiguous bf16 -> ds_write_b64, conflict-free (2-way).
__device__ __forceinline__ void store_qa(const f16v v, short* Ph, short* Pl,
                                         int qa, int qb, int lr, int h,
                                         float aa, float bd, int diagq) {
  const int off = (32 * qb + lr) * RS + 32 * qa + 4 * h;
  short* ph = Ph + off;
  short* pl = Pl + off;
#pragma unroll
  for (int g = 0; g < 4; ++g) {
    s4v vh, vl;
#pragma unroll
    for (int t = 0; t < 4; ++t) {
      float x = aa * v[4 * g + t];
      if (diagq && (t + 8 * g + 4 * h) == lr) x += bd;
      short hh = tb(x);
      vh[t] = hh;
      vl[t] = tb(x - fb(hh));
    }
    *(s4v*)(ph + 8 * g) = vh;
    *(s4v*)(pl + 8 * g) = vl;
  }
}

// T0 = 1.5 I - 0.5 Y, derived elementwise in fragment layout (rows 32q+lr)
__device__ __forceinline__ void derive_T0(const s8v yh[4], const s8v yl[4], int q,
                                          int lr, int h, s8v th[4], s8v tl[4]) {
  const int n = 32 * q + lr;
#pragma unroll
  for (int ks = 0; ks < 4; ++ks) {
#pragma unroll
    for (int e = 0; e < 8; ++e) {
      float y = fb(yh[ks][e]) + fb(yl[ks][e]);
      float t = ((ks * 16 + 8 * h + e) == n ? 1.5f : 0.0f) - 0.5f * y;
      short hh = tb(t);
      th[ks][e] = hh;
      tl[ks][e] = tb(t - fb(hh));
    }
  }
}

// X = Y - I in fragment layout
__device__ __forceinline__ void derive_X(const s8v yh[4], const s8v yl[4], int q,
                                         int lr, int h, s8v xh[4], s8v xl[4]) {
  const int n = 32 * q + lr;
#pragma unroll
  for (int ks = 0; ks < 4; ++ks) {
#pragma unroll
    for (int e = 0; e < 8; ++e) {
      float y = fb(yh[ks][e]) + fb(yl[ks][e]);
      float x = y - ((ks * 16 + 8 * h + e) == n ? 1.0f : 0.0f);
      short hh = tb(x);
      xh[ks][e] = hh;
      xl[ks][e] = tb(x - fb(hh));
    }
  }
}

// Write fragment-layout rows (rows 32q+lr, this wave's 2 ksteps) to planes
__device__ __forceinline__ void write_fr(short* Ph, short* Pl, const s8v fh[4],
                                         const s8v fl[4], int q, int lr, int h,
                                         int qi) {
  const int off = (32 * q + lr) * RS + 8 * h;
  short* ph = Ph + off;
  short* pl = Pl + off;
#pragma unroll
  for (int ks = 0; ks < 4; ++ks) {
    if ((ks >> 1) != qi) continue;  // wave-uniform coverage split
    *(s4v*)(ph + 16 * ks) = __builtin_shufflevector(fh[ks], fh[ks], 0, 1, 2, 3);
    *(s4v*)(ph + 16 * ks + 4) = __builtin_shufflevector(fh[ks], fh[ks], 4, 5, 6, 7);
    *(s4v*)(pl + 16 * ks) = __builtin_shufflevector(fl[ks], fl[ks], 0, 1, 2, 3);
    *(s4v*)(pl + 16 * ks + 4) = __builtin_shufflevector(fl[ks], fl[ks], 4, 5, 6, 7);
  }
}

// Q1 = (1/7) X - (1/6) I written in fragment layout (from cached X frags)
__device__ __forceinline__ void write_Q1(short* Ph, short* Pl, const s8v xh[4],
                                         const s8v xl[4], int q, int lr, int h,
                                         int qi) {
  const int n = 32 * q + lr;
  const int off = n * RS + 8 * h;
#pragma unroll
  for (int ks = 0; ks < 4; ++ks) {
    if ((ks >> 1) != qi) continue;
    s4v vh[2], vl[2];
#pragma unroll
    for (int e = 0; e < 8; ++e) {
      float x = fb(xh[ks][e]) + fb(xl[ks][e]);
      float v = x * (1.0f / 7.0f);
      if ((ks * 16 + 8 * h + e) == n) v -= (1.0f / 6.0f);
      short hh = tb(v);
      vh[e >> 2][e & 3] = hh;
      vl[e >> 2][e & 3] = tb(v - fb(hh));
    }
    *(s4v*)(Ph + off + 16 * ks) = vh[0];
    *(s4v*)(Ph + off + 16 * ks + 4) = vh[1];
    *(s4v*)(Pl + off + 16 * ks) = vl[0];
    *(s4v*)(Pl + off + 16 * ks + 4) = vl[1];
  }
}

extern "C" __global__ void __launch_bounds__(256, 3)
logeig_kernel(const float* __restrict__ in, float* __restrict__ out) {
  __shared__ __align__(16) short sm[6 * PLANE];
  __shared__ float red[4];

  const int b = blockIdx.x, tid = threadIdx.x;
  short* Yh = sm;
  short* Yl = sm + PLANE;
  short* Zh = sm + 2 * PLANE;
  short* Zl = sm + 3 * PLANE;
  short* Th = sm + 4 * PLANE;
  short* Tl = sm + 5 * PLANE;
  float* Ast = (float*)(sm + 2 * PLANE);  // fp32 staging overlaps Z/T planes

  // ---- stage A (coalesced) ----
  {
    const float4* A4 = (const float4*)(in + (size_t)b * 4096);
#pragma unroll
    for (int i = 0; i < 4; ++i) {
      int f = tid + 256 * i;
      float4 v = A4[f];
      int row = f >> 4, col = (f & 15) << 2;
      *(float4*)(Ast + row * RS + col) = v;
    }
  }
  __syncthreads();

  // ---- c = ||A||_inf ; split Y = A/c into bf16 hi/lo planes ----
  const int rr = tid >> 2, cc = tid & 3;
  float av[16];
  {
    const float* rp = Ast + rr * RS + cc * 16;
    float s = 0.f;
#pragma unroll
    for (int i = 0; i < 16; ++i) {
      av[i] = rp[i];
      s += fabsf(av[i]);
    }
    s += __shfl_xor(s, 1);
    s += __shfl_xor(s, 2);
#pragma unroll
    for (int off = 4; off < 64; off <<= 1) s = fmaxf(s, __shfl_xor(s, off));
    if ((tid & 63) == 0) red[tid >> 6] = s;
  }
  __syncthreads();
  const float c = fmaxf(fmaxf(red[0], red[1]), fmaxf(red[2], red[3]));
  const float inv_c = 1.0f / c, log_c = logf(c);
  {
    short* ph = Yh + rr * RS + cc * 16;
    short* pl = Yl + rr * RS + cc * 16;
#pragma unroll
    for (int i = 0; i < 16; ++i) {
      float y = av[i] * inv_c;
      short hh = tb(y);
      ph[i] = hh;
      pl[i] = tb(y - fb(hh));
    }
  }
  __syncthreads();

  const int lane = tid & 63, w = tid >> 6;
  const int lr = lane & 31, h = lane >> 5;
  const int qi = w >> 1, qj = w & 1;
  const int dq = (qi == qj);

  // ---- 3 sqrt levels, coupled Newton-Schulz on MFMA ----
#pragma unroll 1
  for (int lvl = 0; lvl < 3; ++lvl) {
    const int ni = (lvl == 0) ? 8 : ((lvl == 1) ? 6 : 5);
    // it 0: Z=I -> T0 = 1.5I - 0.5Y (derived in frags), Y1 = Y*T0, Z = T0
    {
      s8v Yi_h[4], Yi_l[4], Yj_h[4], Yj_l[4], T0h[4], T0l[4];
      load_fs(Yh, Yl, qi, lr, h, Yi_h, Yi_l);
      load_fs(Yh, Yl, qj, lr, h, Yj_h, Yj_l);
      derive_T0(Yj_h, Yj_l, qj, lr, h, T0h, T0l);
      f16v acc = mm3p(Yi_h, Yi_l, T0h, T0l);  // quadrant (qi,qj)
      __syncthreads();                        // all Y reads done
      store_qa(acc, Yh, Yl, qi, qj, lr, h, 1.f, 0.f, dq);
      write_fr(Zh, Zl, T0h, T0l, qj, lr, h, qi);  // Z := T0
      __syncthreads();
    }
#pragma unroll 1
    for (int it = 1; it < ni; ++it) {
      s8v Zi_h[4], Zi_l[4], Yj_h[4], Yj_l[4];
      load_fs(Zh, Zl, qi, lr, h, Zi_h, Zi_l);
      load_fs(Yh, Yl, qj, lr, h, Yj_h, Yj_l);
      f16v p = mm3p(Zi_h, Zi_l, Yj_h, Yj_l);  // P(qi,qj) = Z*Y
      store_qa(p, Th, Tl, qi, qj, lr, h, -0.5f, 1.5f, dq);  // T = 1.5I - 0.5P
      __syncthreads();  // T visible
      s8v Bh[4], Bl[4];
      load_fs(Th, Tl, qi, lr, h, Bh, Bl);
      f16v ny = mm3p(Yj_h, Yj_l, Bh, Bl);  // Y' quadrant (qj,qi), reuses Y@qj
      load_fs(Th, Tl, qj, lr, h, Bh, Bl);
      f16v nz = mm3p(Zi_h, Zi_l, Bh, Bl);  // Z' quadrant (qi,qj), reuses Z@qi
      __syncthreads();                     // all Y/Z/T reads done
      store_qa(ny, Yh, Yl, qj, qi, lr, h, 1.f, 0.f, dq);
      store_qa(nz, Zh, Zl, qi, qj, lr, h, 1.f, 0.f, dq);
      __syncthreads();
    }
  }

  // ---- log series: X = Y - I (frag-cached), Q in Z planes ----
  s8v Xh[4], Xl[4];
  {
    s8v yh[4], yl[4];
    load_fs(Yh, Yl, qj, lr, h, yh, yl);
    derive_X(yh, yl, qj, lr, h, Xh, Xl);
    write_Q1(Zh, Zl, Xh, Xl, qj, lr, h, qi);  // Q = (1/7)X - (1/6)I
  }
  __syncthreads();

  // Horner: Q = Q*X + coef*I  (X cached in regs; 1 matmul/step)
#pragma unroll
  for (int s = 0; s < 5; ++s) {
    const float coef[5] = {0.2f, -0.25f, 1.f / 3.f, -0.5f, 1.0f};
    s8v Qh[4], Ql[4];
    load_fs(Zh, Zl, qi, lr, h, Qh, Ql);
    f16v q = mm3p(Qh, Ql, Xh, Xl);  // quadrant (qi,qj)
    __syncthreads();
    store_qa(q, Zh, Zl, qi, qj, lr, h, 1.0f, coef[s], dq);
    __syncthreads();
  }

  // ---- final: L = 8*(Q*X) + log(c) I ; abs, sqrt2 off-diag, triu gather ----
  {
    s8v Qh[4], Ql[4];
    load_fs(Zh, Zl, qi, lr, h, Qh, Ql);
    f16v fq = mm3p(Qh, Ql, Xh, Xl);  // quadrant (qi,qj)
    if (qi <= qj) {
      const float SQ2 = 1.41421356237309515f;
      float* ob = out + (size_t)b * 2080;
#pragma unroll
      for (int g = 0; g < 4; ++g) {
#pragma unroll
        for (int t = 0; t < 4; ++t) {
          int rexpr = t + 8 * g + 4 * h;
          int R = 32 * qi + rexpr, C = 32 * qj + lr;
          if (qi < qj || rexpr <= lr) {
            float v = 8.f * fq[4 * g + t] + ((dq && rexpr == lr) ? log_c : 0.f);
            v = fabsf(v) * ((R == C) ? 1.f : SQ2);
            ob[(size_t)(R * 64 - (R * (R - 1)) / 2 - R) + C] = v;
          }
        }
      }
    }
  }
}

extern "C" void kernel_launch(void* const* d_in, const int* in_sizes, int n_in,
                              void* d_out, int out_size, void* d_ws, size_t ws_size,
                              hipStream_t stream) {
  (void)n_in; (void)d_ws; (void)ws_size; (void)out_size;
  const float* in = (const float*)d_in[0];
  float* out = (float*)d_out;
  const int B = in_sizes[0] / 4096;  // 16384
  hipLaunchKernelGGL(logeig_kernel, dim3(B), dim3(256), 0, stream, in, out);
}